// Round 4
// baseline (8551.972 us; speedup 1.0000x reference)
//
#include <hip/hip_runtime.h>
#include <math.h>

#define NT     365
#define NGRID  3000
#define NX     20
#define H      256
#define CPB    15
#define NBLK   (NGRID/CPB)     // 200 blocks, 1 per CU
#define THREADS 1024           // 16 waves, 4 per SIMD

// packed weight sizes (ushorts)
// wpk HI-ONLY: [g 16][kap 16][q 4][lane 64][e 8]
#define WPK_US   (16*16*4*64*8)   // 524,288
#define WPKIN_US (16*2*64*8)      // 16,384

typedef short v8s __attribute__((ext_vector_type(8)));
typedef float v4f __attribute__((ext_vector_type(4)));
#define MFMA_BF16 __builtin_amdgcn_mfma_f32_16x16x32_bf16

__device__ __forceinline__ unsigned short f2bf(float f) {
    unsigned int u = __float_as_uint(f);
    u += 0x7fffu + ((u >> 16) & 1u);          // RTNE
    return (unsigned short)(u >> 16);
}
__device__ __forceinline__ float bf2f(unsigned short h) {
    return __uint_as_float(((unsigned int)h) << 16);
}
__device__ __forceinline__ float sigm(float x)  { return 1.0f / (1.0f + __expf(-x)); }
__device__ __forceinline__ float tanh_f(float x){ return 2.0f * sigm(2.0f * x) - 1.0f; }

// ---------------- weight pre-pack (unchanged) ----------------
__global__ void prep_kernel(const float* __restrict__ w_in,
                            const float* __restrict__ w_ih,
                            const float* __restrict__ w_hh,
                            const float* __restrict__ b_ih,
                            const float* __restrict__ b_hh,
                            unsigned short* __restrict__ wpk,
                            unsigned short* __restrict__ wpkin,
                            float* __restrict__ bsum) {
    int idx = blockIdx.x * 256 + threadIdx.x;
    if (idx < WPK_US) {
        int e    = idx & 7;
        int lane = (idx >> 3) & 63;
        int q    = (idx >> 9) & 3;
        int gk   = idx >> 11;            // 0..255
        int kap  = gk & 15, g = gk >> 4;
        int k = kap * 32 + ((lane >> 4) << 3) + e;
        int j = q * 256 + g * 16 + (lane & 15);
        float wv = (k < 256) ? w_ih[j * 256 + k] : w_hh[j * 256 + (k - 256)];
        wpk[idx] = f2bf(wv);             // hi only
    }
    if (idx < WPKIN_US) {
        int e    = idx & 7;
        int lane = (idx >> 3) & 63;
        int d    = (idx >> 9) & 1;
        int tau  = idx >> 10;            // 0..15
        int k = ((lane >> 4) << 3) + e;
        int n = tau * 16 + (lane & 15);
        float wv = (k < NX + 1) ? w_in[n * (NX + 1) + k] : 0.0f;
        unsigned short hi = f2bf(wv);
        wpkin[idx] = d ? f2bf(wv - bf2f(hi)) : hi;
    }
    if (idx < 4 * H) bsum[idx] = b_ih[idx] + b_hh[idx];
}

// ---------------- main persistent LSTM ----------------
// R12 = R11 resubmit (container infra failure, no counters) with hardened
// barrier codegen:
//  - asm lgkmcnt(0) + sched_barrier(0) fence (rule #18) + builtin s_barrier
//    (the verified 8-phase template pair) instead of barrier-inside-asm.
// Design (unchanged from R11):
//  - lgkm-only barriers: global loads (per-thread reg dests) stay in flight
//    across barriers; no vmcnt(0) drain per phase.
//  - streamed kaps via explicit 1-deep double-buffer (named v8s, static uses).
//  - LDS persists kap 11 full + kap 10 q0..q2 (112KB of weights); kap 10 q3
//    in one 8-reg chunk. Stream 896KB/step through L2.
__global__ __attribute__((amdgpu_flat_work_group_size(THREADS, THREADS),
                          amdgpu_waves_per_eu(4, 4)))
void lstm_main(const float* __restrict__ x,
               const float* __restrict__ y,
               const float* __restrict__ b_in,
               const float* __restrict__ w_out,
               const float* __restrict__ b_out,
               const unsigned short* __restrict__ wpk,
               const unsigned short* __restrict__ wpkin,
               const float* __restrict__ bsum,
               float* __restrict__ out) {
    // fragment-major activation buffers: [kap][lane*8+e], lane = qp*16 + m
    __shared__ __align__(16) unsigned short Agh[16][512];   // 16 KB
    __shared__ __align__(16) unsigned short Agl[16][512];   // 16 KB
    __shared__ __align__(16) unsigned short Xh[512];        // 1 KB
    __shared__ __align__(16) unsigned short Xl[512];        // 1 KB
    __shared__ __align__(16) unsigned short Bw11[16][2048]; // 64 KB kap-11
    __shared__ __align__(16) unsigned short Bw10[16][1536]; // 48 KB kap-10 q0-2
    __shared__ float y_part[16][16];
    // total ~147 KB -> 1 block/CU

    const int tid  = threadIdx.x;
    const int w    = tid >> 6;          // wave 0..15; owns output group g = w
    const int lane = tid & 63;
    const int col  = lane & 15;
    const int quad = lane >> 4;
    const int g0   = blockIdx.x * CPB;

    // per-wave constants: lane owns hidden index jh = w*16 + col
    const int   jh   = w * 16 + col;
    const float b_i  = bsum[jh];
    const float b_f  = bsum[256 + jh];
    const float b_g  = bsum[512 + jh];
    const float b_o  = bsum[768 + jh];
    const float wo   = w_out[jh];
    const float bi_x = b_in[jh];
    const float bout = b_out[0];
    const int   kq_x = jh >> 5;                   // x0 write plane (0..7)
    const int   kq_h = 8 + (jh >> 5);             // h write plane (8..15)
    const int   qp_w = (jh >> 3) & 3;
    const int   e_w  = jh & 7;
    const unsigned short* bbase = wpk + (size_t)(w * 16) * 4 * 512 + lane * 8;
    const unsigned short* bx_hi = wpkin + (w * 2 + 0) * 512 + lane * 8;
    const unsigned short* bx_lo = wpkin + (w * 2 + 1) * 512 + lane * 8;

    // raw barrier: orders LDS (lgkm) only; global loads stay in flight.
    // All cross-wave deps at these barriers are ds_write -> barrier -> ds_read.
#define BAR()                                                           \
    do {                                                                \
        asm volatile("s_waitcnt lgkmcnt(0)" ::: "memory");              \
        __builtin_amdgcn_sched_barrier(0);                              \
        __builtin_amdgcn_s_barrier();                                   \
        __builtin_amdgcn_sched_barrier(0);                              \
    } while (0)

    // zero-init LDS (h planes must be 0 at t=0; pad cols stay 0 forever)
    {
        unsigned int* p;
        p = (unsigned int*)&Agh[0][0];
        for (int i = tid; i < 16 * 256; i += THREADS) p[i] = 0u;
        p = (unsigned int*)&Agl[0][0];
        for (int i = tid; i < 16 * 256; i += THREADS) p[i] = 0u;
        if (tid < 256) ((unsigned int*)&Xh[0])[tid] = 0u;
        if (tid < 256) ((unsigned int*)&Xl[0])[tid] = 0u;
    }

#define LOADK(kap, c) (*(const v8s*)(bbase + ((size_t)(kap) * 4 + (c)) * 512))

    // ---- prologue: LDS-persisted weights (kap 11 full, kap 10 q0-2),
    //      persisted q3 chunk of kap 10, w_in frags, x/y for t=0
    {
        *(v8s*)&Bw11[w][0 * 512 + lane * 8] = LOADK(11, 0);
        *(v8s*)&Bw11[w][1 * 512 + lane * 8] = LOADK(11, 1);
        *(v8s*)&Bw11[w][2 * 512 + lane * 8] = LOADK(11, 2);
        *(v8s*)&Bw11[w][3 * 512 + lane * 8] = LOADK(11, 3);
        *(v8s*)&Bw10[w][0 * 512 + lane * 8] = LOADK(10, 0);
        *(v8s*)&Bw10[w][1 * 512 + lane * 8] = LOADK(10, 1);
        *(v8s*)&Bw10[w][2 * 512 + lane * 8] = LOADK(10, 2);
    }
    const v8s q3b = LOADK(10, 3);           // 8-reg persisted quarter kap
    const v8s bxh = *(const v8s*)bx_hi;     // per-wave constant across steps
    const v8s bxl = *(const v8s*)bx_lo;

    float xv = 0.0f, yv = 0.0f;
    if (tid < CPB * NX) xv = x[(size_t)g0 * NX + tid];
    if (tid < CPB)      yv = y[(size_t)g0 + tid];

    float c_st[4];
    #pragma unroll
    for (int r = 0; r < 4; ++r) c_st[r] = 0.0f;
    __syncthreads();    // one full drain after prologue (one-time cost)

    // pipeline buffers (named, static uses only -> register-promotable)
    v8s sA0, sA1, sA2, sA3;
    v8s sB0, sB1, sB2, sB3;

#define ISSUE(P, KAP)                                                   \
    P##0 = LOADK(KAP, 0); P##1 = LOADK(KAP, 1);                         \
    P##2 = LOADK(KAP, 2); P##3 = LOADK(KAP, 3)

#define GEMM_R(KAP, P)                                                  \
    {                                                                   \
        v8s Ah = *(const v8s*)&Agh[KAP][lane * 8];                      \
        v8s Al = *(const v8s*)&Agl[KAP][lane * 8];                      \
        acc0 = MFMA_BF16(Ah, P##0, acc0, 0, 0, 0);                      \
        acc0 = MFMA_BF16(Al, P##0, acc0, 0, 0, 0);                      \
        acc1 = MFMA_BF16(Ah, P##1, acc1, 0, 0, 0);                      \
        acc1 = MFMA_BF16(Al, P##1, acc1, 0, 0, 0);                      \
        acc2 = MFMA_BF16(Ah, P##2, acc2, 0, 0, 0);                      \
        acc2 = MFMA_BF16(Al, P##2, acc2, 0, 0, 0);                      \
        acc3 = MFMA_BF16(Ah, P##3, acc3, 0, 0, 0);                      \
        acc3 = MFMA_BF16(Al, P##3, acc3, 0, 0, 0);                      \
    }

    for (int t = 0; t < NT; ++t) {
        // ---- P1': stage xcat from prefetched regs (pure LDS writes)
        if (tid < CPB * NX) {
            float v  = xv;
            int cell = tid / NX;
            int k    = tid - cell * NX;
            int pos  = (((k >> 3) << 4) + cell) * 8 + (k & 7);
            unsigned short hi = f2bf(v);
            Xh[pos] = hi;
            Xl[pos] = f2bf(v - bf2f(hi));
        }
        if (tid < CPB) {
            if (!__builtin_isnan(yv)) {
                int pos = (2 * 16 + tid) * 8 + 4;     // k = 20
                unsigned short hi = f2bf(yv);
                Xh[pos] = hi;
                Xl[pos] = f2bf(yv - bf2f(hi));
            }
        }
        ISSUE(sA, 8);                  // kap 8 loads fly across barrier A + X
        BAR();                                         // barrier A (lgkm only)
        ISSUE(sB, 9);                  // kap 9 loads fly across X

        // ---- X: x0 = relu(xcat @ w_in^T + b_in); writes planes 0..7 only
        {
            v8s xah = *(const v8s*)&Xh[lane * 8];
            v8s xal = *(const v8s*)&Xl[lane * 8];
            v4f xacc = {0.0f, 0.0f, 0.0f, 0.0f};
            xacc = MFMA_BF16(xah, bxh, xacc, 0, 0, 0);
            xacc = MFMA_BF16(xah, bxl, xacc, 0, 0, 0);
            xacc = MFMA_BF16(xal, bxh, xacc, 0, 0, 0);
            #pragma unroll
            for (int r = 0; r < 4; ++r) {
                int cell = quad * 4 + r;
                if (cell < CPB) {
                    float v = fmaxf(xacc[r] + bi_x, 0.0f);
                    unsigned short hi = f2bf(v);
                    int pos = (qp_w * 16 + cell) * 8 + e_w;
                    Agh[kq_x][pos] = hi;
                    Agl[kq_x][pos] = f2bf(v - bf2f(hi));
                }
            }
        }
        // no barrier: G part 1 reads planes 8..15, disjoint from X's writes

        // ---- G part 1: h-kaps (streamed 8,9,12..15 pipelined; 10/11 local)
        v4f acc0 = {0.0f, 0.0f, 0.0f, 0.0f};
        v4f acc1 = {0.0f, 0.0f, 0.0f, 0.0f};
        v4f acc2 = {0.0f, 0.0f, 0.0f, 0.0f};
        v4f acc3 = {0.0f, 0.0f, 0.0f, 0.0f};

        GEMM_R(8, sA);   ISSUE(sA, 12);
        GEMM_R(9, sB);   ISSUE(sB, 13);
        GEMM_R(12, sA);  ISSUE(sA, 14);
        GEMM_R(13, sB);  ISSUE(sB, 15);
        GEMM_R(14, sA);  ISSUE(sA, 0);     // kap 0 flies across barrier B
        GEMM_R(15, sB);

        // kap 10: q0-2 from LDS, q3 from persisted regs -- zero L2 traffic
        {
            v8s Bl0 = *(const v8s*)&Bw10[w][0 * 512 + lane * 8];
            v8s Bl1 = *(const v8s*)&Bw10[w][1 * 512 + lane * 8];
            v8s Bl2 = *(const v8s*)&Bw10[w][2 * 512 + lane * 8];
            v8s Ah  = *(const v8s*)&Agh[10][lane * 8];
            v8s Al  = *(const v8s*)&Agl[10][lane * 8];
            acc0 = MFMA_BF16(Ah, Bl0, acc0, 0, 0, 0);
            acc0 = MFMA_BF16(Al, Bl0, acc0, 0, 0, 0);
            acc1 = MFMA_BF16(Ah, Bl1, acc1, 0, 0, 0);
            acc1 = MFMA_BF16(Al, Bl1, acc1, 0, 0, 0);
            acc2 = MFMA_BF16(Ah, Bl2, acc2, 0, 0, 0);
            acc2 = MFMA_BF16(Al, Bl2, acc2, 0, 0, 0);
            acc3 = MFMA_BF16(Ah, q3b, acc3, 0, 0, 0);
            acc3 = MFMA_BF16(Al, q3b, acc3, 0, 0, 0);
        }
        // kap 11 from LDS -- zero L2 traffic
        {
            v8s Bl0 = *(const v8s*)&Bw11[w][0 * 512 + lane * 8];
            v8s Bl1 = *(const v8s*)&Bw11[w][1 * 512 + lane * 8];
            v8s Bl2 = *(const v8s*)&Bw11[w][2 * 512 + lane * 8];
            v8s Bl3 = *(const v8s*)&Bw11[w][3 * 512 + lane * 8];
            v8s Ah  = *(const v8s*)&Agh[11][lane * 8];
            v8s Al  = *(const v8s*)&Agl[11][lane * 8];
            acc0 = MFMA_BF16(Ah, Bl0, acc0, 0, 0, 0);
            acc0 = MFMA_BF16(Al, Bl0, acc0, 0, 0, 0);
            acc1 = MFMA_BF16(Ah, Bl1, acc1, 0, 0, 0);
            acc1 = MFMA_BF16(Al, Bl1, acc1, 0, 0, 0);
            acc2 = MFMA_BF16(Ah, Bl2, acc2, 0, 0, 0);
            acc2 = MFMA_BF16(Al, Bl2, acc2, 0, 0, 0);
            acc3 = MFMA_BF16(Ah, Bl3, acc3, 0, 0, 0);
            acc3 = MFMA_BF16(Al, Bl3, acc3, 0, 0, 0);
        }
        BAR();                                         // barrier B (lgkm only)

        // ---- prefetch x/y for t+1 (flies across barrier C into next P1')
        {
            const int tn = (t + 1 < NT) ? (t + 1) : t;
            if (tid < CPB * NX)
                xv = x[((size_t)tn * NGRID + g0) * NX + tid];
            if (tid < CPB)
                yv = y[(size_t)tn * NGRID + g0 + tid];
        }

        // ---- G part 2: x-kaps 0..7 (x0 ordered by barrier B), pipelined
        GEMM_R(0, sA);   ISSUE(sB, 1);
        GEMM_R(1, sB);   ISSUE(sA, 2);
        GEMM_R(2, sA);   ISSUE(sB, 3);
        GEMM_R(3, sB);   ISSUE(sA, 4);
        GEMM_R(4, sA);   ISSUE(sB, 5);
        GEMM_R(5, sB);   ISSUE(sA, 6);
        GEMM_R(6, sA);   ISSUE(sB, 7);
        GEMM_R(7, sB);

        // ---- E: pointwise LSTM + h writeback + y partial
        // (E writes planes 8..15; all reads of 8..15 ended before barrier B)
        {
            float yp[4];
            #pragma unroll
            for (int r = 0; r < 4; ++r) {
                int cell = quad * 4 + r;
                float iv = acc0[r] + b_i;
                float fv = acc1[r] + b_f;
                float gv = acc2[r] + b_g;
                float ov = acc3[r] + b_o;
                float c  = fmaf(sigm(fv), c_st[r], sigm(iv) * tanh_f(gv));
                c_st[r]  = c;
                float h  = sigm(ov) * tanh_f(c);
                yp[r] = 0.0f;
                if (cell < CPB) {
                    unsigned short hi = f2bf(h);
                    int pos = (qp_w * 16 + cell) * 8 + e_w;
                    Agh[kq_h][pos] = hi;
                    Agl[kq_h][pos] = f2bf(h - bf2f(hi));
                    yp[r] = h * wo;
                }
            }
            #pragma unroll
            for (int r = 0; r < 4; ++r) {
                float p = yp[r];
                p += __shfl_xor(p, 1);
                p += __shfl_xor(p, 2);
                p += __shfl_xor(p, 4);
                p += __shfl_xor(p, 8);
                if (col == 0)
                    y_part[w][quad * 4 + r] = p;
            }
        }
        BAR();                                         // barrier C (lgkm only)

        // ---- P5: finalize y, store, feed back into xcat k=20
        // (no loop-end barrier: next barrier A orders these LDS writes vs the
        //  next X-phase reads; k=20 obs overwrite is same-thread)
        if (tid < CPB) {
            float yfin = bout;
            #pragma unroll
            for (int w2 = 0; w2 < 16; ++w2) yfin += y_part[w2][tid];
            out[(size_t)t * NGRID + g0 + tid] = yfin;
            int pos = (2 * 16 + tid) * 8 + 4;             // k = 20
            unsigned short hi = f2bf(yfin);
            Xh[pos] = hi;
            Xl[pos] = f2bf(yfin - bf2f(hi));
        }
    }
}

extern "C" void kernel_launch(void* const* d_in, const int* in_sizes, int n_in,
                              void* d_out, int out_size, void* d_ws, size_t ws_size,
                              hipStream_t stream) {
    const float* x     = (const float*)d_in[0];
    const float* y     = (const float*)d_in[1];
    const float* w_in  = (const float*)d_in[2];
    const float* b_in  = (const float*)d_in[3];
    const float* w_ih  = (const float*)d_in[4];
    const float* b_ih  = (const float*)d_in[5];
    const float* w_hh  = (const float*)d_in[6];
    const float* b_hh  = (const float*)d_in[7];
    const float* w_out = (const float*)d_in[8];
    const float* b_out = (const float*)d_in[9];

    unsigned short* wpk   = (unsigned short*)d_ws;
    unsigned short* wpkin = wpk + WPK_US;
    float*          bsum  = (float*)(wpkin + WPKIN_US);
    float*          out   = (float*)d_out;

    prep_kernel<<<(WPK_US + 255) / 256, 256, 0, stream>>>(
        w_in, w_ih, w_hh, b_ih, b_hh, wpk, wpkin, bsum);
    lstm_main<<<NBLK, THREADS, 0, stream>>>(
        x, y, b_in, w_out, b_out, wpk, wpkin, bsum, out);
}

// Round 5
// 5618.962 us; speedup vs baseline: 1.5220x; 1.5220x over previous
//
#include <hip/hip_runtime.h>
#include <math.h>

#define NT     365
#define NGRID  3000
#define NX     20
#define H      256
#define CPB    15
#define NBLK   (NGRID/CPB)     // 200 blocks, 1 per CU
#define THREADS 1024           // 16 waves, 4 per SIMD

// packed weight sizes (ushorts)
// wpk HI-ONLY, pi-ordered: [g 16][pi 16][q 4][lane 64][e 8]
//   pi = streaming order: old kaps {8,9,12,13,14,15,0..7} -> pi 0..13 (streamed)
//                         old kaps {10,11}               -> pi 14,15 (LDS-persisted)
#define WPK_US   (16*16*4*64*8)   // 524,288
#define WPKIN_US (16*2*64*8)      // 16,384

typedef short v8s __attribute__((ext_vector_type(8)));
typedef float v4f __attribute__((ext_vector_type(4)));
#define MFMA_BF16 __builtin_amdgcn_mfma_f32_16x16x32_bf16

__device__ __forceinline__ unsigned short f2bf(float f) {
    unsigned int u = __float_as_uint(f);
    u += 0x7fffu + ((u >> 16) & 1u);          // RTNE
    return (unsigned short)(u >> 16);
}
__device__ __forceinline__ float bf2f(unsigned short h) {
    return __uint_as_float(((unsigned int)h) << 16);
}
__device__ __forceinline__ float sigm(float x)  { return 1.0f / (1.0f + __expf(-x)); }
__device__ __forceinline__ float tanh_f(float x){ return 2.0f * sigm(2.0f * x) - 1.0f; }

// ---------------- weight pre-pack (pi-reordered) ----------------
__global__ void prep_kernel(const float* __restrict__ w_in,
                            const float* __restrict__ w_ih,
                            const float* __restrict__ w_hh,
                            const float* __restrict__ b_ih,
                            const float* __restrict__ b_hh,
                            unsigned short* __restrict__ wpk,
                            unsigned short* __restrict__ wpkin,
                            float* __restrict__ bsum) {
    int idx = blockIdx.x * 256 + threadIdx.x;
    if (idx < WPK_US) {
        int e    = idx & 7;
        int lane = (idx >> 3) & 63;
        int q    = (idx >> 9) & 3;
        int gk   = idx >> 11;            // 0..255
        int pi   = gk & 15, g = gk >> 4;
        // pi -> old kap: {0,1}->{8,9}; {2..5}->{12..15}; {6..13}->{0..7}; {14,15}->{10,11}
        int kap = (pi < 2) ? pi + 8 : (pi < 6) ? pi + 10 : (pi < 14) ? pi - 6 : pi - 4;
        int k = kap * 32 + ((lane >> 4) << 3) + e;
        int j = q * 256 + g * 16 + (lane & 15);
        float wv = (k < 256) ? w_ih[j * 256 + k] : w_hh[j * 256 + (k - 256)];
        wpk[idx] = f2bf(wv);             // hi only
    }
    if (idx < WPKIN_US) {
        int e    = idx & 7;
        int lane = (idx >> 3) & 63;
        int d    = (idx >> 9) & 1;
        int tau  = idx >> 10;            // 0..15
        int k = ((lane >> 4) << 3) + e;
        int n = tau * 16 + (lane & 15);
        float wv = (k < NX + 1) ? w_in[n * (NX + 1) + k] : 0.0f;
        unsigned short hi = f2bf(wv);
        wpkin[idx] = d ? f2bf(wv - bf2f(hi)) : hi;
    }
    if (idx < 4 * H) bsum[idx] = b_ih[idx] + b_hh[idx];
}

// ---------------- main persistent LSTM ----------------
// R13: fix R4's spill cascade (VGPR stuck at 64, scratch thrash -> 11.4GB HBM).
//  Root causes: (a) 128-reg unified cap/wave at 16 waves/block leaves no room
//  for 48-reg persistence; (b) 56 flattened LOADK sites with >13-bit offsets
//  materialized dozens of 64-bit address pairs.
//  Fixes:
//  - wpk repacked in STREAMING ORDER (pi): one loop-carried stream pointer,
//    +4KB/batch, chunk loads at imm offsets 0/1024/2048/3072. One addr pair.
//  - Activation planes relabeled to the same pi order: A-plane reads are a
//    second loop-carried pointer, +1KB/batch.
//  - NO register-persisted weights. LDS persists pi=15 full + pi=14 q0..q2
//    (112 KB); pi14-q3 via one named reg loaded per step (deep flight).
//  - 2-deep rotation (A/B, 32 regs) in rolled unroll-1 pair loops.
//  - Raw lgkm-only barriers (validated correct in R4): weight/x/y loads
//    stay in flight across barriers.
__global__ __attribute__((amdgpu_flat_work_group_size(THREADS, THREADS),
                          amdgpu_waves_per_eu(4, 4)))
void lstm_main(const float* __restrict__ x,
               const float* __restrict__ y,
               const float* __restrict__ b_in,
               const float* __restrict__ w_out,
               const float* __restrict__ b_out,
               const unsigned short* __restrict__ wpk,
               const unsigned short* __restrict__ wpkin,
               const float* __restrict__ bsum,
               float* __restrict__ out) {
    // fragment-major activation buffers: [pi][lane*8+e], lane = qp*16 + m
    __shared__ __align__(16) unsigned short Agh[16][512];   // 16 KB
    __shared__ __align__(16) unsigned short Agl[16][512];   // 16 KB
    __shared__ __align__(16) unsigned short Xh[512];        // 1 KB
    __shared__ __align__(16) unsigned short Xl[512];        // 1 KB
    __shared__ __align__(16) unsigned short BwB[16][2048];  // 64 KB pi-15
    __shared__ __align__(16) unsigned short BwA[16][1536];  // 48 KB pi-14 q0-2
    __shared__ float y_part[16][16];
    // total ~147 KB -> 1 block/CU

    const int tid  = threadIdx.x;
    const int w    = tid >> 6;          // wave 0..15; owns output group g = w
    const int lane = tid & 63;
    const int col  = lane & 15;
    const int quad = lane >> 4;
    const int g0   = blockIdx.x * CPB;

    // per-wave constants: lane owns hidden index jh = w*16 + col
    const int   jh   = w * 16 + col;
    const float b_i  = bsum[jh];
    const float b_f  = bsum[256 + jh];
    const float b_g  = bsum[512 + jh];
    const float b_o  = bsum[768 + jh];
    const float wo   = w_out[jh];
    const float bi_x = b_in[jh];
    const float bout = b_out[0];
    const int   hs   = jh >> 5;                   // 0..7
    const int   pi_x = hs + 6;                    // x0 write plane (6..13)
    const int   pi_h = (hs < 2) ? hs : ((hs < 4) ? hs + 12 : hs - 2); // h plane
    const int   qp_w = (jh >> 3) & 3;
    const int   e_w  = jh & 7;
    const unsigned short* bbase = wpk + (size_t)w * 16 * 2048 + lane * 8;
    const unsigned short* q3p   = bbase + (size_t)(14 * 4 + 3) * 512;
    const unsigned short* bx_hi = wpkin + (w * 2 + 0) * 512 + lane * 8;
    const unsigned short* bx_lo = wpkin + (w * 2 + 1) * 512 + lane * 8;

    // raw barrier: orders LDS (lgkm) only; global loads stay in flight.
    // All cross-wave deps at these barriers are ds_write -> barrier -> ds_read.
#define BAR()                                                           \
    do {                                                                \
        asm volatile("s_waitcnt lgkmcnt(0)" ::: "memory");              \
        __builtin_amdgcn_sched_barrier(0);                              \
        __builtin_amdgcn_s_barrier();                                   \
        __builtin_amdgcn_sched_barrier(0);                              \
    } while (0)

    // zero-init LDS (h planes must be 0 at t=0; pad cols stay 0 forever)
    {
        unsigned int* p;
        p = (unsigned int*)&Agh[0][0];
        for (int i = tid; i < 16 * 256; i += THREADS) p[i] = 0u;
        p = (unsigned int*)&Agl[0][0];
        for (int i = tid; i < 16 * 256; i += THREADS) p[i] = 0u;
        if (tid < 256) ((unsigned int*)&Xh[0])[tid] = 0u;
        if (tid < 256) ((unsigned int*)&Xl[0])[tid] = 0u;
    }

    // ---- prologue: LDS-persisted weights (pi15 full, pi14 q0-2), w_in frags,
    //      x/y for t=0 (one-time; static big offsets are fine here)
    {
        *(v8s*)&BwB[w][0 * 512 + lane * 8] = *(const v8s*)(bbase + (15*4+0)*512);
        *(v8s*)&BwB[w][1 * 512 + lane * 8] = *(const v8s*)(bbase + (15*4+1)*512);
        *(v8s*)&BwB[w][2 * 512 + lane * 8] = *(const v8s*)(bbase + (15*4+2)*512);
        *(v8s*)&BwB[w][3 * 512 + lane * 8] = *(const v8s*)(bbase + (15*4+3)*512);
        *(v8s*)&BwA[w][0 * 512 + lane * 8] = *(const v8s*)(bbase + (14*4+0)*512);
        *(v8s*)&BwA[w][1 * 512 + lane * 8] = *(const v8s*)(bbase + (14*4+1)*512);
        *(v8s*)&BwA[w][2 * 512 + lane * 8] = *(const v8s*)(bbase + (14*4+2)*512);
    }
    const v8s bxh = *(const v8s*)bx_hi;     // per-wave constant across steps
    const v8s bxl = *(const v8s*)bx_lo;

    float xv = 0.0f, yv = 0.0f;
    if (tid < CPB * NX) xv = x[(size_t)g0 * NX + tid];
    if (tid < CPB)      yv = y[(size_t)g0 + tid];

    float c_st[4];
    #pragma unroll
    for (int r = 0; r < 4; ++r) c_st[r] = 0.0f;
    __syncthreads();    // one full drain after prologue (one-time cost)

    // 2-deep rotating pipeline buffers (named, static uses only)
    v8s pA0, pA1, pA2, pA3;
    v8s pB0, pB1, pB2, pB3;
    const unsigned short* sp = bbase;       // stream pointer, pi-order

    // issue one batch (4 chunks at imm offsets) and advance the pointer
#define ISSUEP(P)                                                       \
    do {                                                                \
        P##0 = *(const v8s*)(sp);                                       \
        P##1 = *(const v8s*)(sp + 512);                                 \
        P##2 = *(const v8s*)(sp + 1024);                                \
        P##3 = *(const v8s*)(sp + 1536);                                \
        sp += 2048;                                                     \
    } while (0)

    // consume the next A-plane (linear pi order) against buffer P
#define GEMM_P(P)                                                       \
    do {                                                                \
        v8s Ah = *(const v8s*)ah; ah += 512;                            \
        v8s Al = *(const v8s*)al; al += 512;                            \
        acc0 = MFMA_BF16(Ah, P##0, acc0, 0, 0, 0);                      \
        acc0 = MFMA_BF16(Al, P##0, acc0, 0, 0, 0);                      \
        acc1 = MFMA_BF16(Ah, P##1, acc1, 0, 0, 0);                      \
        acc1 = MFMA_BF16(Al, P##1, acc1, 0, 0, 0);                      \
        acc2 = MFMA_BF16(Ah, P##2, acc2, 0, 0, 0);                      \
        acc2 = MFMA_BF16(Al, P##2, acc2, 0, 0, 0);                      \
        acc3 = MFMA_BF16(Ah, P##3, acc3, 0, 0, 0);                      \
        acc3 = MFMA_BF16(Al, P##3, acc3, 0, 0, 0);                      \
    } while (0)

    ISSUEP(pA);                 // pi 0 (in flight across t=0 prologue phases)
    ISSUEP(pB);                 // pi 1

    for (int t = 0; t < NT; ++t) {
        // ---- P1': stage xcat from prefetched regs (pure LDS writes)
        if (tid < CPB * NX) {
            float v  = xv;
            int cell = tid / NX;
            int k    = tid - cell * NX;
            int pos  = (((k >> 3) << 4) + cell) * 8 + (k & 7);
            unsigned short hi = f2bf(v);
            Xh[pos] = hi;
            Xl[pos] = f2bf(v - bf2f(hi));
        }
        if (tid < CPB) {
            if (!__builtin_isnan(yv)) {
                int pos = (2 * 16 + tid) * 8 + 4;     // k = 20
                unsigned short hi = f2bf(yv);
                Xh[pos] = hi;
                Xl[pos] = f2bf(yv - bf2f(hi));
            }
        }
        const v8s q3v = *(const v8s*)q3p;   // pi14-q3: flies across BAR-A + X
        BAR();                                         // barrier A (lgkm only)

        // ---- X: x0 = relu(xcat @ w_in^T + b_in); writes planes 6..13 only
        {
            v8s xah = *(const v8s*)&Xh[lane * 8];
            v8s xal = *(const v8s*)&Xl[lane * 8];
            v4f xacc = {0.0f, 0.0f, 0.0f, 0.0f};
            xacc = MFMA_BF16(xah, bxh, xacc, 0, 0, 0);
            xacc = MFMA_BF16(xah, bxl, xacc, 0, 0, 0);
            xacc = MFMA_BF16(xal, bxh, xacc, 0, 0, 0);
            #pragma unroll
            for (int r = 0; r < 4; ++r) {
                int cell = quad * 4 + r;
                if (cell < CPB) {
                    float v = fmaxf(xacc[r] + bi_x, 0.0f);
                    unsigned short hi = f2bf(v);
                    int pos = (qp_w * 16 + cell) * 8 + e_w;
                    Agh[pi_x][pos] = hi;
                    Agl[pi_x][pos] = f2bf(v - bf2f(hi));
                }
            }
        }
        // no barrier: part 1 reads planes 0..5,14,15 -- disjoint from X writes

        // ---- G part 1: h-batches pi 0..5 (streamed) + pi 14,15 (LDS)
        v4f acc0 = {0.0f, 0.0f, 0.0f, 0.0f};
        v4f acc1 = {0.0f, 0.0f, 0.0f, 0.0f};
        v4f acc2 = {0.0f, 0.0f, 0.0f, 0.0f};
        v4f acc3 = {0.0f, 0.0f, 0.0f, 0.0f};
        const unsigned short* ah = &Agh[0][lane * 8];
        const unsigned short* al = &Agl[0][lane * 8];

        #pragma unroll 1
        for (int b = 0; b < 3; ++b) {
            GEMM_P(pA); ISSUEP(pA);
            GEMM_P(pB); ISSUEP(pB);
        }
        // pi 14: q0-2 from LDS, q3 from q3v -- zero L2 traffic
        {
            v8s Bl0 = *(const v8s*)&BwA[w][0 * 512 + lane * 8];
            v8s Bl1 = *(const v8s*)&BwA[w][1 * 512 + lane * 8];
            v8s Bl2 = *(const v8s*)&BwA[w][2 * 512 + lane * 8];
            v8s Ah  = *(const v8s*)&Agh[14][lane * 8];
            v8s Al  = *(const v8s*)&Agl[14][lane * 8];
            acc0 = MFMA_BF16(Ah, Bl0, acc0, 0, 0, 0);
            acc0 = MFMA_BF16(Al, Bl0, acc0, 0, 0, 0);
            acc1 = MFMA_BF16(Ah, Bl1, acc1, 0, 0, 0);
            acc1 = MFMA_BF16(Al, Bl1, acc1, 0, 0, 0);
            acc2 = MFMA_BF16(Ah, Bl2, acc2, 0, 0, 0);
            acc2 = MFMA_BF16(Al, Bl2, acc2, 0, 0, 0);
            acc3 = MFMA_BF16(Ah, q3v, acc3, 0, 0, 0);
            acc3 = MFMA_BF16(Al, q3v, acc3, 0, 0, 0);
        }
        // pi 15 from LDS -- zero L2 traffic
        {
            v8s Bl0 = *(const v8s*)&BwB[w][0 * 512 + lane * 8];
            v8s Bl1 = *(const v8s*)&BwB[w][1 * 512 + lane * 8];
            v8s Bl2 = *(const v8s*)&BwB[w][2 * 512 + lane * 8];
            v8s Bl3 = *(const v8s*)&BwB[w][3 * 512 + lane * 8];
            v8s Ah  = *(const v8s*)&Agh[15][lane * 8];
            v8s Al  = *(const v8s*)&Agl[15][lane * 8];
            acc0 = MFMA_BF16(Ah, Bl0, acc0, 0, 0, 0);
            acc0 = MFMA_BF16(Al, Bl0, acc0, 0, 0, 0);
            acc1 = MFMA_BF16(Ah, Bl1, acc1, 0, 0, 0);
            acc1 = MFMA_BF16(Al, Bl1, acc1, 0, 0, 0);
            acc2 = MFMA_BF16(Ah, Bl2, acc2, 0, 0, 0);
            acc2 = MFMA_BF16(Al, Bl2, acc2, 0, 0, 0);
            acc3 = MFMA_BF16(Ah, Bl3, acc3, 0, 0, 0);
            acc3 = MFMA_BF16(Al, Bl3, acc3, 0, 0, 0);
        }
        BAR();                                         // barrier B (orders X writes)

        // ---- prefetch x/y for t+1 (flies across barrier C into next P1')
        {
            const int tn = (t + 1 < NT) ? (t + 1) : t;
            if (tid < CPB * NX)
                xv = x[((size_t)tn * NGRID + g0) * NX + tid];
            if (tid < CPB)
                yv = y[(size_t)tn * NGRID + g0 + tid];
        }

        // ---- G part 2: x-batches pi 6..13 (x0 ordered by barrier B)
        #pragma unroll 1
        for (int b = 0; b < 3; ++b) {
            GEMM_P(pA); ISSUEP(pA);
            GEMM_P(pB); ISSUEP(pB);
        }
        // last pair: wrap the stream pointer and issue next step's pi 0,1
        GEMM_P(pA);
        sp = bbase;
        ISSUEP(pA);                         // next-step pi 0
        GEMM_P(pB);
        ISSUEP(pB);                         // next-step pi 1

        // ---- E: pointwise LSTM + h writeback + y partial
        // (E writes planes 0..5,14,15; all reads of those ended pre-BAR-B)
        {
            float yp[4];
            #pragma unroll
            for (int r = 0; r < 4; ++r) {
                int cell = quad * 4 + r;
                float iv = acc0[r] + b_i;
                float fv = acc1[r] + b_f;
                float gv = acc2[r] + b_g;
                float ov = acc3[r] + b_o;
                float c  = fmaf(sigm(fv), c_st[r], sigm(iv) * tanh_f(gv));
                c_st[r]  = c;
                float h  = sigm(ov) * tanh_f(c);
                yp[r] = 0.0f;
                if (cell < CPB) {
                    unsigned short hi = f2bf(h);
                    int pos = (qp_w * 16 + cell) * 8 + e_w;
                    Agh[pi_h][pos] = hi;
                    Agl[pi_h][pos] = f2bf(h - bf2f(hi));
                    yp[r] = h * wo;
                }
            }
            #pragma unroll
            for (int r = 0; r < 4; ++r) {
                float p = yp[r];
                p += __shfl_xor(p, 1);
                p += __shfl_xor(p, 2);
                p += __shfl_xor(p, 4);
                p += __shfl_xor(p, 8);
                if (col == 0)
                    y_part[w][quad * 4 + r] = p;
            }
        }
        BAR();                                         // barrier C (lgkm only)

        // ---- P5: finalize y, store, feed back into xcat k=20
        // (no loop-end barrier: next barrier A orders these LDS writes vs the
        //  next X-phase reads; k=20 obs overwrite is same-thread)
        if (tid < CPB) {
            float yfin = bout;
            #pragma unroll
            for (int w2 = 0; w2 < 16; ++w2) yfin += y_part[w2][tid];
            out[(size_t)t * NGRID + g0 + tid] = yfin;
            int pos = (2 * 16 + tid) * 8 + 4;             // k = 20
            unsigned short hi = f2bf(yfin);
            Xh[pos] = hi;
            Xl[pos] = f2bf(yfin - bf2f(hi));
        }
    }
}

extern "C" void kernel_launch(void* const* d_in, const int* in_sizes, int n_in,
                              void* d_out, int out_size, void* d_ws, size_t ws_size,
                              hipStream_t stream) {
    const float* x     = (const float*)d_in[0];
    const float* y     = (const float*)d_in[1];
    const float* w_in  = (const float*)d_in[2];
    const float* b_in  = (const float*)d_in[3];
    const float* w_ih  = (const float*)d_in[4];
    const float* b_ih  = (const float*)d_in[5];
    const float* w_hh  = (const float*)d_in[6];
    const float* b_hh  = (const float*)d_in[7];
    const float* w_out = (const float*)d_in[8];
    const float* b_out = (const float*)d_in[9];

    unsigned short* wpk   = (unsigned short*)d_ws;
    unsigned short* wpkin = wpk + WPK_US;
    float*          bsum  = (float*)(wpkin + WPKIN_US);
    float*          out   = (float*)d_out;

    prep_kernel<<<(WPK_US + 255) / 256, 256, 0, stream>>>(
        w_in, w_ih, w_hh, b_ih, b_hh, wpk, wpkin, bsum);
    lstm_main<<<NBLK, THREADS, 0, stream>>>(
        x, y, b_in, w_out, b_out, wpk, wpkin, bsum, out);
}